// Round 5
// baseline (413.392 us; speedup 1.0000x reference)
//
#include <hip/hip_runtime.h>

// TreeLRU: B=16, N=4095 heap, IN=OUT=512, S=256.
// Round 9: (1) cvt was MLP-bound (4 loads in flight -> 1.4 TB/s predicted,
// 1.64 measured): now 16 float4 loads into named regs before any store.
// (2) GEMM: BK=32 with the SIMPLE round-6 schedule and 2x16KB buffers ->
// 32KB LDS -> 4 blocks/CU (occupancy was pinned at 2 blocks/CU in every
// prior config; all pipes <16% = latency-bound, TLP is the lever).
// Round-3's BK=32 failure was confounded: 4 bufs = 64KB = still 2/CU plus
// an exotic counted-vmcnt schedule. LDS slot perm (kc+(row>>1))&3 keeps
// ds_read_b128 2-way-free with linear global_load_lds dest.
// tree_up2 unchanged (attribution).

#define ROWS 65520
#define KDIM 512

typedef __attribute__((ext_vector_type(8))) short bf16x8;
typedef __attribute__((ext_vector_type(4))) float f32x4;

__device__ __forceinline__ unsigned short f2bf(float f) {
    unsigned int u = __float_as_uint(f);
    unsigned int r = (u + 0x7FFFu + ((u >> 16) & 1u)) >> 16;
    return (unsigned short)r;
}
__device__ __forceinline__ float b2f(unsigned short h) {
    return __uint_as_float(((unsigned int)h) << 16);
}
__device__ __forceinline__ float b2f_lo(unsigned int p) {      // low bf16 of pair
    return __uint_as_float(p << 16);
}
__device__ __forceinline__ float b2f_hi(unsigned int p) {      // high bf16 of pair
    return __uint_as_float(p & 0xFFFF0000u);
}

// ---------------- merged prep: prep_M | prep_C | prep_bias | cvt ----------------
#define PC_BASE   1024
#define PB_BASE   2048
#define CVT_BASE  2176
#define CVT_BLKS  2048
#define PREP_GRID 4224
#define CVT_N4    8386560          // ROWS*512/4
#define CVT_STR   (CVT_BLKS * 256) // 524288

__global__ __launch_bounds__(256) void prep_all(const float* __restrict__ x,
                                                unsigned short* __restrict__ x16,
                                                const float* __restrict__ W,
                                                const float* __restrict__ Bre,
                                                const float* __restrict__ Bim,
                                                const float* __restrict__ gamma_log,
                                                unsigned short* __restrict__ M16,
                                                const float* __restrict__ bin,
                                                float* __restrict__ biasc,
                                                const float* __restrict__ Cre,
                                                const float* __restrict__ Cim,
                                                unsigned short* __restrict__ C16) {
    __shared__ float Bs[16][17];
    __shared__ float Ws[16][17];
    const int blk = blockIdx.x;
    const int t = threadIdx.x;

    if (blk < PC_BASE) {
        // ---- prep_M: 32x32 grid of 16x16 tiles ----
        const int bx = blk & 31;       // j tile
        const int by = blk >> 5;       // cc tile
        const int tx = t & 15;
        const int ty = t >> 4;
        const int j  = bx * 16 + tx;
        const int cc = by * 16 + ty;
        const float* Bsel = (cc < 256) ? (Bre + (size_t)cc * 512)
                                       : (Bim + (size_t)(cc - 256) * 512);
        float acc = 0.f;
        for (int kt = 0; kt < 512; kt += 16) {
            Bs[ty][tx] = Bsel[kt + tx];
            Ws[ty][tx] = W[(size_t)(kt + ty) * 512 + j];
            __syncthreads();
#pragma unroll
            for (int k = 0; k < 16; ++k) acc += Bs[ty][k] * Ws[k][tx];
            __syncthreads();
        }
        float g = expf(gamma_log[cc & 255]);
        M16[(size_t)cc * 512 + j] = f2bf(acc * g);
    } else if (blk < PB_BASE) {
        // ---- prep_C ----
        int idx = (blk - PC_BASE) * 256 + t;   // 0..262143
        int o = idx >> 9;
        int s = idx & 511;
        float v = (s < 256) ? Cre[(size_t)o * 256 + s] : -Cim[(size_t)o * 256 + (s - 256)];
        C16[idx] = f2bf(v);
    } else if (blk < CVT_BASE) {
        // ---- prep_bias: 4 channels per block, one wave each ----
        const int c = (blk - PB_BASE) * 4 + (t >> 6);   // 0..511
        const int lane = t & 63;
        const float* Bsel = (c < 256) ? (Bre + (size_t)c * 512)
                                      : (Bim + (size_t)(c - 256) * 512);
        float acc = 0.f;
#pragma unroll
        for (int i = lane; i < 512; i += 64) acc += bin[i] * Bsel[i];
#pragma unroll
        for (int off = 32; off > 0; off >>= 1) acc += __shfl_down(acc, off, 64);
        if (lane == 0) biasc[c] = acc * expf(gamma_log[c & 255]);
    } else {
        // ---- cvt f32 -> bf16: 16 loads in flight, then 16 cvt+stores ----
        const int i = (blk - CVT_BASE) * 256 + t;     // 0..524287
        const float4* src = (const float4*)x;
        ushort4* dst = (ushort4*)x16;
        if (i < CVT_N4 - 15 * CVT_STR) {
            float4 v0  = src[i];
            float4 v1  = src[i +  1 * CVT_STR];
            float4 v2  = src[i +  2 * CVT_STR];
            float4 v3  = src[i +  3 * CVT_STR];
            float4 v4  = src[i +  4 * CVT_STR];
            float4 v5  = src[i +  5 * CVT_STR];
            float4 v6  = src[i +  6 * CVT_STR];
            float4 v7  = src[i +  7 * CVT_STR];
            float4 v8  = src[i +  8 * CVT_STR];
            float4 v9  = src[i +  9 * CVT_STR];
            float4 v10 = src[i + 10 * CVT_STR];
            float4 v11 = src[i + 11 * CVT_STR];
            float4 v12 = src[i + 12 * CVT_STR];
            float4 v13 = src[i + 13 * CVT_STR];
            float4 v14 = src[i + 14 * CVT_STR];
            float4 v15 = src[i + 15 * CVT_STR];
#define CVT1(K, V)                                                             \
            { ushort4 o; o.x = f2bf(V.x); o.y = f2bf(V.y);                     \
              o.z = f2bf(V.z); o.w = f2bf(V.w); dst[i + (K) * CVT_STR] = o; }
            CVT1(0, v0)  CVT1(1, v1)  CVT1(2, v2)  CVT1(3, v3)
            CVT1(4, v4)  CVT1(5, v5)  CVT1(6, v6)  CVT1(7, v7)
            CVT1(8, v8)  CVT1(9, v9)  CVT1(10, v10) CVT1(11, v11)
            CVT1(12, v12) CVT1(13, v13) CVT1(14, v14) CVT1(15, v15)
#undef CVT1
        } else {
#pragma unroll
            for (int k = 0; k < 16; ++k) {
                int idx = i + k * CVT_STR;
                if (idx < CVT_N4) {
                    float4 v = src[idx];
                    ushort4 o;
                    o.x = f2bf(v.x); o.y = f2bf(v.y); o.z = f2bf(v.z); o.w = f2bf(v.w);
                    dst[idx] = o;
                }
            }
        }
    }
}

// ---------------- bf16 MFMA GEMM: C = A @ B^T (+bias), K=N=512 ----------------
// Persistent: 512 blocks; block p: xcd=p&7, q=p>>3, colblk=q&3, rg=q>>2.
// Sweeps 4 row-tiles rowblk(j) = xcd*64 + rg*4 + j (colblk-siblings share A
// panel in the same XCD L2; B panel L2/L1-hot).
// BK=32: 16 K-tiles, 2 LDS buffers of 16KB -> 32KB total -> 4 blocks/CU.
// Round-6 schedule: STAGE(next, buf^1) -> setprio -> 16 MFMA -> syncthreads.
// LDS [row][slot]: slot holds logical K-chunk kc = (slot-(row>>1))&3;
// read slot = ((lane>>4)+(row>>1))&3 -> 8 distinct banks x 2-way = free.
template <bool OUT_BF16>
__global__ __launch_bounds__(256) void gemm_mfma(const unsigned short* __restrict__ A,
                                                 const unsigned short* __restrict__ Bm,
                                                 const float* __restrict__ bias,
                                                 void* __restrict__ Cout,
                                                 int Mrows) {
    __shared__ __align__(16) unsigned short As[2][128 * 32];
    __shared__ __align__(16) unsigned short Bs[2][128 * 32];
    const int t = threadIdx.x;
    const int lane = t & 63;
    const int w = t >> 6;
    const int wr = (w >> 1) * 64;
    const int wc = (w & 1) * 64;
    const int p = blockIdx.x;               // 0..511
    const int xcd = p & 7;
    const int q = p >> 3;                   // 0..63
    const int colblk = q & 3;
    const int rg = q >> 2;                  // 0..15
    const int col0 = colblk * 128;

    // per-thread stage geometry: chunks c_ = t and t+256; row=c_>>2, slot=c_&3
    int arow[2], akoff[2], ldsoff[2];
    const unsigned short* gbB[2];
#pragma unroll
    for (int qq = 0; qq < 2; ++qq) {
        int c_   = qq * 256 + t;           // 0..511
        int row_ = c_ >> 2;
        int sl_  = c_ & 3;
        int kc_  = (sl_ - (row_ >> 1)) & 3;   // inverse of read perm
        arow[qq]  = row_;
        akoff[qq] = kc_ * 8;
        ldsoff[qq] = c_ * 8;
        gbB[qq] = Bm + (size_t)(col0 + row_) * KDIM + kc_ * 8;
    }
    const unsigned short* gaB[2];

#define SET_TILE_A(ROW0)                                                       \
    do {                                                                       \
        _Pragma("unroll")                                                      \
        for (int qq = 0; qq < 2; ++qq) {                                       \
            int ar_ = (ROW0) + arow[qq]; if (ar_ >= Mrows) ar_ = Mrows - 1;    \
            gaB[qq] = A + (size_t)ar_ * KDIM + akoff[qq];                      \
        }                                                                      \
    } while (0)

#define STAGE(pb, KT)                                                          \
    do {                                                                       \
        _Pragma("unroll")                                                      \
        for (int qq = 0; qq < 2; ++qq) {                                       \
            __builtin_amdgcn_global_load_lds(                                  \
                (const __attribute__((address_space(1))) unsigned int*)(gaB[qq] + (KT)), \
                (__attribute__((address_space(3))) unsigned int*)(&As[pb][ldsoff[qq]]), \
                16, 0, 0);                                                     \
            __builtin_amdgcn_global_load_lds(                                  \
                (const __attribute__((address_space(1))) unsigned int*)(gbB[qq] + (KT)), \
                (__attribute__((address_space(3))) unsigned int*)(&Bs[pb][ldsoff[qq]]), \
                16, 0, 0);                                                     \
        }                                                                      \
    } while (0)

    f32x4 acc[4][4] = {};

    int rowblk = xcd * 64 + rg * 4;        // tile j=0
    int row0 = rowblk * 128;
    int kt0 = (rowblk & 15) * 32;
    SET_TILE_A(row0);
    STAGE(0, kt0);
    __syncthreads();                        // tile0 K0 resident

    int cur = 0;
    for (int j = 0; j < 4; ++j) {
        for (int it = 0; it < 16; ++it) {
            if (it < 15) {
                STAGE(cur ^ 1, (kt0 + (it + 1) * 32) & 511);
            } else if (j < 3) {
                // cross-tile prefetch: tile j+1, its first K-tile
                const int nrowblk = rowblk + 1;
                SET_TILE_A(nrowblk * 128);
                STAGE(cur ^ 1, (nrowblk & 15) * 32);
            }
            __builtin_amdgcn_s_setprio(1);
            {
                bf16x8 af[4], bfr[4];
#pragma unroll
                for (int i = 0; i < 4; ++i) {
                    int row = wr + i * 16 + (lane & 15);
                    int sa  = ((lane >> 4) + (row >> 1)) & 3;
                    af[i] = *(const bf16x8*)(&As[cur][row * 32 + sa * 8]);
                    int colr = wc + i * 16 + (lane & 15);
                    int sb  = ((lane >> 4) + (colr >> 1)) & 3;
                    bfr[i] = *(const bf16x8*)(&Bs[cur][colr * 32 + sb * 8]);
                }
#pragma unroll
                for (int i = 0; i < 4; ++i)
#pragma unroll
                    for (int jj = 0; jj < 4; ++jj)
                        acc[i][jj] = __builtin_amdgcn_mfma_f32_16x16x32_bf16(
                            af[i], bfr[jj], acc[i][jj], 0, 0, 0);
            }
            __builtin_amdgcn_s_setprio(0);
            __syncthreads();    // publishes prefetched tile
            cur ^= 1;
        }

        // epilogue for tile j (overlaps flight of tile j+1's first K-tile)
        const int cq = lane >> 4;
        const int cl = lane & 15;
#pragma unroll
        for (int i = 0; i < 4; ++i) {
#pragma unroll
            for (int jj = 0; jj < 4; ++jj) {
#pragma unroll
                for (int r = 0; r < 4; ++r) {
                    int grow = row0 + wr + i * 16 + cq * 4 + r;
                    int gcol = col0 + wc + jj * 16 + cl;
                    if (grow < Mrows) {
                        float v = acc[i][jj][r];
                        if (bias) v += bias[gcol];
                        if (OUT_BF16)
                            ((unsigned short*)Cout)[(size_t)grow * 512 + gcol] = f2bf(v);
                        else
                            ((float*)Cout)[(size_t)grow * 512 + gcol] = v;
                    }
                    acc[i][jj][r] = 0.f;
                }
            }
        }

        rowblk += 1;
        row0 = rowblk * 128;
        kt0 = (rowblk & 15) * 32;
    }
#undef STAGE
#undef SET_TILE_A
}

// ---------------- tree recurrence, v2 (unchanged) ----------------
template <int E>
__global__ __launch_bounds__(256) void tree_up2(unsigned short* __restrict__ buf,
                                                const float* __restrict__ nu_log,
                                                const float* __restrict__ theta_log,
                                                int root_base, int nroots) {
    const int b = blockIdx.x;
    const int h = threadIdx.x >> 7;
    const int j2 = (threadIdx.x & 127) * 2;        // channel pair base
    const int rr = blockIdx.y * 2 + h;
    if (rr >= nroots) return;
    const int rs = root_base + rr;
    constexpr int LEAVES = 1 << E;
    constexpr int NODES = LEAVES - 1;

    float lr0, li0, lr1, li1;
    { const float lam = expf(-expf(nu_log[j2]));     const float th = expf(theta_log[j2]);
      lr0 = lam * cosf(th); li0 = lam * sinf(th); }
    { const float lam = expf(-expf(nu_log[j2 + 1])); const float th = expf(theta_log[j2 + 1]);
      lr1 = lam * cosf(th); li1 = lam * sinf(th); }
    const size_t base = (size_t)b * 4095;

    // 1) issue ALL loads (62 x 4B per thread, independent) ...
    unsigned int pr[LEAVES], pi[LEAVES];
    const int nbL = ((rs + 1) << E) - 1;
#pragma unroll
    for (int i = 0; i < LEAVES; ++i) {
        const size_t r = (base + nbL + i) * 512;
        pr[i] = *(const unsigned int*)(buf + r + j2);
        pi[i] = *(const unsigned int*)(buf + r + 256 + j2);
    }
    unsigned int qr[NODES], qi[NODES];
#pragma unroll
    for (int e = E - 1; e >= 0; --e) {
#pragma unroll
        for (int i = 0; i < (1 << e); ++i) {
            const int idx = LEAVES - (2 << e) + i;
            const size_t r = (base + (((rs + 1) << e) - 1) + i) * 512;
            qr[idx] = *(const unsigned int*)(buf + r + j2);
            qi[idx] = *(const unsigned int*)(buf + r + 256 + j2);
        }
    }
    // ... 2) and only then start consuming (pins MLP; prevents load sinking)
    __builtin_amdgcn_sched_barrier(0);

    float vr0[LEAVES], vi0[LEAVES], vr1[LEAVES], vi1[LEAVES];
#pragma unroll
    for (int i = 0; i < LEAVES; ++i) {
        vr0[i] = b2f_lo(pr[i]); vr1[i] = b2f_hi(pr[i]);
        vi0[i] = b2f_lo(pi[i]); vi1[i] = b2f_hi(pi[i]);
    }
#pragma unroll
    for (int e = E - 1; e >= 0; --e) {
#pragma unroll
        for (int i = 0; i < (1 << e); ++i) {
            const int idx = LEAVES - (2 << e) + i;
            const float cr0 = vr0[2 * i] + vr0[2 * i + 1];
            const float ci0 = vi0[2 * i] + vi0[2 * i + 1];
            const float cr1 = vr1[2 * i] + vr1[2 * i + 1];
            const float ci1 = vi1[2 * i] + vi1[2 * i + 1];
            const float hr0 = lr0 * cr0 - li0 * ci0 + b2f_lo(qr[idx]);
            const float hi0 = lr0 * ci0 + li0 * cr0 + b2f_lo(qi[idx]);
            const float hr1 = lr1 * cr1 - li1 * ci1 + b2f_hi(qr[idx]);
            const float hi1 = lr1 * ci1 + li1 * cr1 + b2f_hi(qi[idx]);
            const size_t r = (base + (((rs + 1) << e) - 1) + i) * 512;
            *(unsigned int*)(buf + r + j2) =
                (unsigned int)f2bf(hr0) | ((unsigned int)f2bf(hr1) << 16);
            *(unsigned int*)(buf + r + 256 + j2) =
                (unsigned int)f2bf(hi0) | ((unsigned int)f2bf(hi1) << 16);
            vr0[i] = hr0; vi0[i] = hi0; vr1[i] = hr1; vi1[i] = hi1;
        }
    }
}

extern "C" void kernel_launch(void* const* d_in, const int* in_sizes, int n_in,
                              void* d_out, int out_size, void* d_ws, size_t ws_size,
                              hipStream_t stream) {
    const float* x         = (const float*)d_in[0];
    const float* W_in      = (const float*)d_in[2];
    const float* b_in      = (const float*)d_in[3];
    const float* nu_log    = (const float*)d_in[4];
    const float* theta_log = (const float*)d_in[5];
    const float* gamma_log = (const float*)d_in[6];
    const float* B_re      = (const float*)d_in[7];
    const float* B_im      = (const float*)d_in[8];
    const float* C_re      = (const float*)d_in[9];
    const float* C_im      = (const float*)d_in[10];
    float* out = (float*)d_out;

    char* ws = (char*)d_ws;
    const size_t HB = (size_t)ROWS * 512 * 2;   // 67,092,480 bytes
    unsigned short* x16   = (unsigned short*)ws;
    unsigned short* hb16  = (unsigned short*)(ws + HB);
    unsigned short* M16   = (unsigned short*)(ws + 2 * HB);
    unsigned short* C16   = (unsigned short*)(ws + 2 * HB + 512 * 512 * 2);
    float*          biasc = (float*)(ws + 2 * HB + 2 * 512 * 512 * 2);

    prep_all<<<PREP_GRID, 256, 0, stream>>>(x, x16, W_in, B_re, B_im, gamma_log,
                                            M16, b_in, biasc, C_re, C_im, C16);

    gemm_mfma<true><<<512, 256, 0, stream>>>(x16, M16, biasc, hb16, ROWS);

    // levels 10..7 (roots at level 7: nodes 127..254), then 6..3 (roots at
    // level 3: nodes 7..14), then 2..0 (root 0).
    tree_up2<4><<<dim3(16, 64), 256, 0, stream>>>(hb16, nu_log, theta_log, 127, 128);
    tree_up2<4><<<dim3(16, 4),  256, 0, stream>>>(hb16, nu_log, theta_log, 7, 8);
    tree_up2<3><<<dim3(16, 1),  256, 0, stream>>>(hb16, nu_log, theta_log, 0, 1);

    gemm_mfma<false><<<512, 256, 0, stream>>>(hb16, C16, nullptr, out, ROWS);
}

// Round 6
// 404.889 us; speedup vs baseline: 1.0210x; 1.0210x over previous
//
#include <hip/hip_runtime.h>

// TreeLRU: B=16, N=4095 heap, IN=OUT=512, S=256.
// Round 10: (1) gemm reverted to round-8 persistent BK=64 structure (best
// known, <=85.8us; round-9's BK=32 regressed and its occupancy test was
// confounded by the 512-block grid cap). (2) x16 conversion pass DELETED:
// gemm1 reads x (f32) directly via T14 reg-staging (global f32 -> regs
// before MFMA cluster; convert+ds_write after), saving cvt's 201MB of HBM
// traffic + a dispatch. B-operand staging stays global_load_lds. gemm2
// (bf16 A) keeps the pure global_load_lds path.
// prep_all = prep_M | prep_C | prep_bias only. tree_up2 unchanged.

#define ROWS 65520
#define KDIM 512

typedef __attribute__((ext_vector_type(8))) short bf16x8;
typedef __attribute__((ext_vector_type(4))) float f32x4;

__device__ __forceinline__ unsigned short f2bf(float f) {
    unsigned int u = __float_as_uint(f);
    unsigned int r = (u + 0x7FFFu + ((u >> 16) & 1u)) >> 16;
    return (unsigned short)r;
}
__device__ __forceinline__ float b2f(unsigned short h) {
    return __uint_as_float(((unsigned int)h) << 16);
}
__device__ __forceinline__ float b2f_lo(unsigned int p) {      // low bf16 of pair
    return __uint_as_float(p << 16);
}
__device__ __forceinline__ float b2f_hi(unsigned int p) {      // high bf16 of pair
    return __uint_as_float(p & 0xFFFF0000u);
}

// ---------------- merged prep: prep_M | prep_C | prep_bias ----------------
#define PC_BASE   1024
#define PB_BASE   2048
#define PREP_GRID 2176

__global__ __launch_bounds__(256) void prep_all(const float* __restrict__ W,
                                                const float* __restrict__ Bre,
                                                const float* __restrict__ Bim,
                                                const float* __restrict__ gamma_log,
                                                unsigned short* __restrict__ M16,
                                                const float* __restrict__ bin,
                                                float* __restrict__ biasc,
                                                const float* __restrict__ Cre,
                                                const float* __restrict__ Cim,
                                                unsigned short* __restrict__ C16) {
    __shared__ float Bs[16][17];
    __shared__ float Ws[16][17];
    const int blk = blockIdx.x;
    const int t = threadIdx.x;

    if (blk < PC_BASE) {
        // ---- prep_M: 32x32 grid of 16x16 tiles ----
        const int bx = blk & 31;       // j tile
        const int by = blk >> 5;       // cc tile
        const int tx = t & 15;
        const int ty = t >> 4;
        const int j  = bx * 16 + tx;
        const int cc = by * 16 + ty;
        const float* Bsel = (cc < 256) ? (Bre + (size_t)cc * 512)
                                       : (Bim + (size_t)(cc - 256) * 512);
        float acc = 0.f;
        for (int kt = 0; kt < 512; kt += 16) {
            Bs[ty][tx] = Bsel[kt + tx];
            Ws[ty][tx] = W[(size_t)(kt + ty) * 512 + j];
            __syncthreads();
#pragma unroll
            for (int k = 0; k < 16; ++k) acc += Bs[ty][k] * Ws[k][tx];
            __syncthreads();
        }
        float g = expf(gamma_log[cc & 255]);
        M16[(size_t)cc * 512 + j] = f2bf(acc * g);
    } else if (blk < PB_BASE) {
        // ---- prep_C ----
        int idx = (blk - PC_BASE) * 256 + t;   // 0..262143
        int o = idx >> 9;
        int s = idx & 511;
        float v = (s < 256) ? Cre[(size_t)o * 256 + s] : -Cim[(size_t)o * 256 + (s - 256)];
        C16[idx] = f2bf(v);
    } else {
        // ---- prep_bias: 4 channels per block, one wave each ----
        const int c = (blk - PB_BASE) * 4 + (t >> 6);   // 0..511
        const int lane = t & 63;
        const float* Bsel = (c < 256) ? (Bre + (size_t)c * 512)
                                      : (Bim + (size_t)(c - 256) * 512);
        float acc = 0.f;
#pragma unroll
        for (int i = lane; i < 512; i += 64) acc += bin[i] * Bsel[i];
#pragma unroll
        for (int off = 32; off > 0; off >>= 1) acc += __shfl_down(acc, off, 64);
        if (lane == 0) biasc[c] = acc * expf(gamma_log[c & 255]);
    }
}

// ---------------- bf16 MFMA GEMM: C = A @ B^T (+bias), K=N=512 ----------------
// Persistent: 512 blocks; block p: xcd=p&7, q=p>>3, colblk=q&3, rg=q>>2.
// Sweeps 4 row-tiles rowblk(j) = xcd*64 + rg*4 + j. Round-8 inner schedule:
// 128x128 tile, 4 waves, BK=64, 2 LDS buffers, STAGE(next) at iter top,
// setprio around 32 MFMA, __syncthreads at bottom. Cross-tile prefetch at
// it=7; epilogue overlaps next tile's first-K flight.
// A_F32 variant (gemm1): A staged via regs (8 float4 loads issued BEFORE the
// MFMA cluster; f32->bf16 convert + ds_write_b128 AFTER it, T14-style).
// LDS layout identical in both variants (slot kc holds logical chunk
// kc^(row&7); reads use kca=(kgc+(lane>>4))^(row&7)).
template <bool A_F32, bool OUT_BF16>
__global__ __launch_bounds__(256) void gemm_mfma(const void* __restrict__ Ain,
                                                 const unsigned short* __restrict__ Bm,
                                                 const float* __restrict__ bias,
                                                 void* __restrict__ Cout,
                                                 int Mrows) {
    __shared__ __align__(16) unsigned short As[2][128 * 64];
    __shared__ __align__(16) unsigned short Bs[2][128 * 64];
    const unsigned short* A16 = (const unsigned short*)Ain;
    const float* A32 = (const float*)Ain;
    const int t = threadIdx.x;
    const int lane = t & 63;
    const int w = t >> 6;
    const int wr = (w >> 1) * 64;
    const int wc = (w & 1) * 64;
    const int p = blockIdx.x;               // 0..511
    const int xcd = p & 7;
    const int q = p >> 3;                   // 0..63
    const int colblk = q & 3;
    const int rg = q >> 2;                  // 0..15
    const int col0 = colblk * 128;

    // per-thread stage geometry (tile-invariant): chunks c_ = qq*256+t
    int arow[4], akoff[4], ldsoff[4];
    const unsigned short* gbB[4];
#pragma unroll
    for (int qq = 0; qq < 4; ++qq) {
        int c_   = qq * 256 + t;           // chunk id 0..1023
        int row_ = c_ >> 3;
        int kc_  = c_ & 7;
        int kg_  = kc_ ^ (row_ & 7);
        arow[qq]  = row_;
        akoff[qq] = kg_ * 8;               // element offset within K-tile
        ldsoff[qq] = c_ * 8;
        gbB[qq] = Bm + (size_t)(col0 + row_) * KDIM + kg_ * 8;
    }
    const unsigned short* ga16[4];
    const float* ga32[4];
    float4 fa[4][2];                        // A_F32 staging regs (unrolled = static)

#define SET_TILE_A(ROW0)                                                       \
    do {                                                                       \
        _Pragma("unroll")                                                      \
        for (int qq = 0; qq < 4; ++qq) {                                       \
            int ar_ = (ROW0) + arow[qq]; if (ar_ >= Mrows) ar_ = Mrows - 1;    \
            if constexpr (A_F32)                                               \
                ga32[qq] = A32 + (size_t)ar_ * KDIM + akoff[qq];               \
            else                                                               \
                ga16[qq] = A16 + (size_t)ar_ * KDIM + akoff[qq];               \
        }                                                                      \
    } while (0)

#define STAGE_B(pb, KT)                                                        \
    do {                                                                       \
        _Pragma("unroll")                                                      \
        for (int qq = 0; qq < 4; ++qq)                                         \
            __builtin_amdgcn_global_load_lds(                                  \
                (const __attribute__((address_space(1))) unsigned int*)(gbB[qq] + (KT)), \
                (__attribute__((address_space(3))) unsigned int*)(&Bs[pb][ldsoff[qq]]), \
                16, 0, 0);                                                     \
    } while (0)

#define STAGE_A16(pb, KT)                                                      \
    do {                                                                       \
        _Pragma("unroll")                                                      \
        for (int qq = 0; qq < 4; ++qq)                                         \
            __builtin_amdgcn_global_load_lds(                                  \
                (const __attribute__((address_space(1))) unsigned int*)(ga16[qq] + (KT)), \
                (__attribute__((address_space(3))) unsigned int*)(&As[pb][ldsoff[qq]]), \
                16, 0, 0);                                                     \
    } while (0)

#define LOAD_A32(KT)                                                           \
    do {                                                                       \
        _Pragma("unroll")                                                      \
        for (int qq = 0; qq < 4; ++qq) {                                       \
            fa[qq][0] = *(const float4*)(ga32[qq] + (KT));                     \
            fa[qq][1] = *(const float4*)(ga32[qq] + (KT) + 4);                 \
        }                                                                      \
    } while (0)

#define WRITE_A32(pb)                                                          \
    do {                                                                       \
        _Pragma("unroll")                                                      \
        for (int qq = 0; qq < 4; ++qq) {                                       \
            uint4 u;                                                           \
            u.x = (unsigned int)f2bf(fa[qq][0].x) | ((unsigned int)f2bf(fa[qq][0].y) << 16); \
            u.y = (unsigned int)f2bf(fa[qq][0].z) | ((unsigned int)f2bf(fa[qq][0].w) << 16); \
            u.z = (unsigned int)f2bf(fa[qq][1].x) | ((unsigned int)f2bf(fa[qq][1].y) << 16); \
            u.w = (unsigned int)f2bf(fa[qq][1].z) | ((unsigned int)f2bf(fa[qq][1].w) << 16); \
            *(uint4*)(&As[pb][ldsoff[qq]]) = u;                                \
        }                                                                      \
    } while (0)

    f32x4 acc[4][4] = {};

    int rowblk = xcd * 64 + rg * 4;        // tile j=0
    int row0 = rowblk * 128;
    int kt0 = (rowblk & 7) * 64;
    SET_TILE_A(row0);
    if constexpr (A_F32) {
        LOAD_A32(kt0);
        STAGE_B(0, kt0);
        WRITE_A32(0);                       // compiler inserts vmcnt wait for fa
    } else {
        STAGE_A16(0, kt0);
        STAGE_B(0, kt0);
    }
    __syncthreads();                        // tile0 K0 resident

    int cur = 0;
    for (int j = 0; j < 4; ++j) {
        for (int it = 0; it < 8; ++it) {
            const bool st = (it < 7) || (j < 3);
            int nkt = 0;
            if (it < 7) {
                nkt = (kt0 + (it + 1) * 64) & 511;
            } else if (j < 3) {
                const int nrowblk = rowblk + 1;
                SET_TILE_A(nrowblk * 128);
                nkt = (nrowblk & 7) * 64;
            }
            if (st) {
                if constexpr (A_F32) {
                    LOAD_A32(nkt);          // issue f32 A loads (hide under MFMA)
                    STAGE_B(cur ^ 1, nkt);
                    __builtin_amdgcn_sched_barrier(0);  // pin issue above MFMA
                } else {
                    STAGE_A16(cur ^ 1, nkt);
                    STAGE_B(cur ^ 1, nkt);
                }
            }
            __builtin_amdgcn_s_setprio(1);
#pragma unroll
            for (int kk = 0; kk < 64; kk += 32) {
                const int kgc = kk >> 3;  // 0 or 4
                bf16x8 af[4], bfr[4];
#pragma unroll
                for (int i = 0; i < 4; ++i) {
                    int row = wr + i * 16 + (lane & 15);
                    int kca = (kgc + (lane >> 4)) ^ (row & 7);
                    af[i] = *(const bf16x8*)(&As[cur][row * 64 + kca * 8]);
                    int colr = wc + i * 16 + (lane & 15);
                    int kcb = (kgc + (lane >> 4)) ^ (colr & 7);
                    bfr[i] = *(const bf16x8*)(&Bs[cur][colr * 64 + kcb * 8]);
                }
#pragma unroll
                for (int i = 0; i < 4; ++i)
#pragma unroll
                    for (int jj = 0; jj < 4; ++jj)
                        acc[i][jj] = __builtin_amdgcn_mfma_f32_16x16x32_bf16(
                            af[i], bfr[jj], acc[i][jj], 0, 0, 0);
            }
            __builtin_amdgcn_s_setprio(0);
            if (st) {
                if constexpr (A_F32) WRITE_A32(cur ^ 1);  // cvt + ds_write (T14 late-write)
            }
            __syncthreads();    // publishes prefetched tile
            cur ^= 1;
        }

        // epilogue for tile j (overlaps flight of tile j+1's K0)
        const int cq = lane >> 4;
        const int cl = lane & 15;
#pragma unroll
        for (int i = 0; i < 4; ++i) {
#pragma unroll
            for (int jj = 0; jj < 4; ++jj) {
#pragma unroll
                for (int r = 0; r < 4; ++r) {
                    int grow = row0 + wr + i * 16 + cq * 4 + r;
                    int gcol = col0 + wc + jj * 16 + cl;
                    if (grow < Mrows) {
                        float v = acc[i][jj][r];
                        if (bias) v += bias[gcol];
                        if (OUT_BF16)
                            ((unsigned short*)Cout)[(size_t)grow * 512 + gcol] = f2bf(v);
                        else
                            ((float*)Cout)[(size_t)grow * 512 + gcol] = v;
                    }
                    acc[i][jj][r] = 0.f;
                }
            }
        }

        rowblk += 1;
        row0 = rowblk * 128;
        kt0 = (rowblk & 7) * 64;
    }
#undef WRITE_A32
#undef LOAD_A32
#undef STAGE_A16
#undef STAGE_B
#undef SET_TILE_A
}

// ---------------- tree recurrence, v2 (unchanged) ----------------
template <int E>
__global__ __launch_bounds__(256) void tree_up2(unsigned short* __restrict__ buf,
                                                const float* __restrict__ nu_log,
                                                const float* __restrict__ theta_log,
                                                int root_base, int nroots) {
    const int b = blockIdx.x;
    const int h = threadIdx.x >> 7;
    const int j2 = (threadIdx.x & 127) * 2;        // channel pair base
    const int rr = blockIdx.y * 2 + h;
    if (rr >= nroots) return;
    const int rs = root_base + rr;
    constexpr int LEAVES = 1 << E;
    constexpr int NODES = LEAVES - 1;

    float lr0, li0, lr1, li1;
    { const float lam = expf(-expf(nu_log[j2]));     const float th = expf(theta_log[j2]);
      lr0 = lam * cosf(th); li0 = lam * sinf(th); }
    { const float lam = expf(-expf(nu_log[j2 + 1])); const float th = expf(theta_log[j2 + 1]);
      lr1 = lam * cosf(th); li1 = lam * sinf(th); }
    const size_t base = (size_t)b * 4095;

    // 1) issue ALL loads (62 x 4B per thread, independent) ...
    unsigned int pr[LEAVES], pi[LEAVES];
    const int nbL = ((rs + 1) << E) - 1;
#pragma unroll
    for (int i = 0; i < LEAVES; ++i) {
        const size_t r = (base + nbL + i) * 512;
        pr[i] = *(const unsigned int*)(buf + r + j2);
        pi[i] = *(const unsigned int*)(buf + r + 256 + j2);
    }
    unsigned int qr[NODES], qi[NODES];
#pragma unroll
    for (int e = E - 1; e >= 0; --e) {
#pragma unroll
        for (int i = 0; i < (1 << e); ++i) {
            const int idx = LEAVES - (2 << e) + i;
            const size_t r = (base + (((rs + 1) << e) - 1) + i) * 512;
            qr[idx] = *(const unsigned int*)(buf + r + j2);
            qi[idx] = *(const unsigned int*)(buf + r + 256 + j2);
        }
    }
    // ... 2) and only then start consuming (pins MLP; prevents load sinking)
    __builtin_amdgcn_sched_barrier(0);

    float vr0[LEAVES], vi0[LEAVES], vr1[LEAVES], vi1[LEAVES];
#pragma unroll
    for (int i = 0; i < LEAVES; ++i) {
        vr0[i] = b2f_lo(pr[i]); vr1[i] = b2f_hi(pr[i]);
        vi0[i] = b2f_lo(pi[i]); vi1[i] = b2f_hi(pi[i]);
    }
#pragma unroll
    for (int e = E - 1; e >= 0; --e) {
#pragma unroll
        for (int i = 0; i < (1 << e); ++i) {
            const int idx = LEAVES - (2 << e) + i;
            const float cr0 = vr0[2 * i] + vr0[2 * i + 1];
            const float ci0 = vi0[2 * i] + vi0[2 * i + 1];
            const float cr1 = vr1[2 * i] + vr1[2 * i + 1];
            const float ci1 = vi1[2 * i] + vi1[2 * i + 1];
            const float hr0 = lr0 * cr0 - li0 * ci0 + b2f_lo(qr[idx]);
            const float hi0 = lr0 * ci0 + li0 * cr0 + b2f_lo(qi[idx]);
            const float hr1 = lr1 * cr1 - li1 * ci1 + b2f_hi(qr[idx]);
            const float hi1 = lr1 * ci1 + li1 * cr1 + b2f_hi(qi[idx]);
            const size_t r = (base + (((rs + 1) << e) - 1) + i) * 512;
            *(unsigned int*)(buf + r + j2) =
                (unsigned int)f2bf(hr0) | ((unsigned int)f2bf(hr1) << 16);
            *(unsigned int*)(buf + r + 256 + j2) =
                (unsigned int)f2bf(hi0) | ((unsigned int)f2bf(hi1) << 16);
            vr0[i] = hr0; vi0[i] = hi0; vr1[i] = hr1; vi1[i] = hi1;
        }
    }
}

extern "C" void kernel_launch(void* const* d_in, const int* in_sizes, int n_in,
                              void* d_out, int out_size, void* d_ws, size_t ws_size,
                              hipStream_t stream) {
    const float* x         = (const float*)d_in[0];
    const float* W_in      = (const float*)d_in[2];
    const float* b_in      = (const float*)d_in[3];
    const float* nu_log    = (const float*)d_in[4];
    const float* theta_log = (const float*)d_in[5];
    const float* gamma_log = (const float*)d_in[6];
    const float* B_re      = (const float*)d_in[7];
    const float* B_im      = (const float*)d_in[8];
    const float* C_re      = (const float*)d_in[9];
    const float* C_im      = (const float*)d_in[10];
    float* out = (float*)d_out;

    char* ws = (char*)d_ws;
    const size_t HB = (size_t)ROWS * 512 * 2;   // 67,092,480 bytes
    unsigned short* hb16  = (unsigned short*)ws;
    unsigned short* M16   = (unsigned short*)(ws + HB);
    unsigned short* C16   = (unsigned short*)(ws + HB + 512 * 512 * 2);
    float*          biasc = (float*)(ws + HB + 2 * 512 * 512 * 2);

    prep_all<<<PREP_GRID, 256, 0, stream>>>(W_in, B_re, B_im, gamma_log,
                                            M16, b_in, biasc, C_re, C_im, C16);

    // gemm1: A = x (f32, converted in-kernel), out bf16 + bias
    gemm_mfma<true, true><<<512, 256, 0, stream>>>(x, M16, biasc, hb16, ROWS);

    // levels 10..7 (roots at level 7: nodes 127..254), then 6..3 (roots at
    // level 3: nodes 7..14), then 2..0 (root 0).
    tree_up2<4><<<dim3(16, 64), 256, 0, stream>>>(hb16, nu_log, theta_log, 127, 128);
    tree_up2<4><<<dim3(16, 4),  256, 0, stream>>>(hb16, nu_log, theta_log, 7, 8);
    tree_up2<3><<<dim3(16, 1),  256, 0, stream>>>(hb16, nu_log, theta_log, 0, 1);

    // gemm2: A = hb16 (bf16), out f32, no bias
    gemm_mfma<false, false><<<512, 256, 0, stream>>>(hb16, C16, nullptr, out, ROWS);
}